// Round 15
// baseline (39.909 us; speedup 1.0000x reference)
//
#include <hip/hip_runtime.h>

#define T_DIM 1024

typedef short short8 __attribute__((ext_vector_type(8)));
typedef float f32x4  __attribute__((ext_vector_type(4)));

__device__ __forceinline__ unsigned pk_bf16(float lo, float hi) {
    unsigned r;
    asm("v_cvt_pk_bf16_f32 %0, %1, %2" : "=v"(r) : "v"(lo), "v"(hi));
    return r;
}

// Pack K (3,8,256) f32 -> bf16 fragments; k-row 24 (kb==3,e==0) carries bias
// (B-side partner is a constant bf16(1.0) in caps_kernel).
__global__ void kpack_kernel(const float* __restrict__ K,
                             const float* __restrict__ bias,
                             uint4* __restrict__ Kp) {
    const int kb  = blockIdx.x;
    const int col = threadIdx.x;
    uint4 wv = make_uint4(0u, 0u, 0u, 0u);
    if (kb < 3) {
        const float* kp = K + kb * 8 * 256 + col;
        wv.x = pk_bf16(kp[0 * 256], kp[1 * 256]);
        wv.y = pk_bf16(kp[2 * 256], kp[3 * 256]);
        wv.z = pk_bf16(kp[4 * 256], kp[5 * 256]);
        wv.w = pk_bf16(kp[6 * 256], kp[7 * 256]);
    } else {
        wv.x = pk_bf16(bias[col], 0.f);
    }
    Kp[kb * 256 + col] = wv;
}

// Single-instruction DPP allreduces over 16-lane rows (R10, verified).
__device__ __forceinline__ void allred_add16_x4(float& a, float& b, float& c, float& d) {
    asm volatile(
        "s_nop 1\n\t"
        "v_add_f32_dpp %0,%0,%0 row_ror:8 row_mask:0xf bank_mask:0xf\n\t"
        "v_add_f32_dpp %1,%1,%1 row_ror:8 row_mask:0xf bank_mask:0xf\n\t"
        "v_add_f32_dpp %2,%2,%2 row_ror:8 row_mask:0xf bank_mask:0xf\n\t"
        "v_add_f32_dpp %3,%3,%3 row_ror:8 row_mask:0xf bank_mask:0xf\n\t"
        "v_add_f32_dpp %0,%0,%0 row_ror:4 row_mask:0xf bank_mask:0xf\n\t"
        "v_add_f32_dpp %1,%1,%1 row_ror:4 row_mask:0xf bank_mask:0xf\n\t"
        "v_add_f32_dpp %2,%2,%2 row_ror:4 row_mask:0xf bank_mask:0xf\n\t"
        "v_add_f32_dpp %3,%3,%3 row_ror:4 row_mask:0xf bank_mask:0xf\n\t"
        "v_add_f32_dpp %0,%0,%0 row_ror:2 row_mask:0xf bank_mask:0xf\n\t"
        "v_add_f32_dpp %1,%1,%1 row_ror:2 row_mask:0xf bank_mask:0xf\n\t"
        "v_add_f32_dpp %2,%2,%2 row_ror:2 row_mask:0xf bank_mask:0xf\n\t"
        "v_add_f32_dpp %3,%3,%3 row_ror:2 row_mask:0xf bank_mask:0xf\n\t"
        "v_add_f32_dpp %0,%0,%0 row_ror:1 row_mask:0xf bank_mask:0xf\n\t"
        "v_add_f32_dpp %1,%1,%1 row_ror:1 row_mask:0xf bank_mask:0xf\n\t"
        "v_add_f32_dpp %2,%2,%2 row_ror:1 row_mask:0xf bank_mask:0xf\n\t"
        "v_add_f32_dpp %3,%3,%3 row_ror:1 row_mask:0xf bank_mask:0xf"
        : "+v"(a), "+v"(b), "+v"(c), "+v"(d));
}
__device__ __forceinline__ float allred_add16_s(float v) {
    asm volatile(
        "s_nop 1\n\t"
        "v_add_f32_dpp %0,%0,%0 row_ror:8 row_mask:0xf bank_mask:0xf\n\t"
        "s_nop 1\n\t"
        "v_add_f32_dpp %0,%0,%0 row_ror:4 row_mask:0xf bank_mask:0xf\n\t"
        "s_nop 1\n\t"
        "v_add_f32_dpp %0,%0,%0 row_ror:2 row_mask:0xf bank_mask:0xf\n\t"
        "s_nop 1\n\t"
        "v_add_f32_dpp %0,%0,%0 row_ror:1 row_mask:0xf bank_mask:0xf"
        : "+v"(v));
    return v;
}

// One block per (b,t), 4 waves, ZERO LDS, zero barriers, zero fences.
// Conv transposed: U^T = Kmat^T * X^T. MFMA tile (qt,oti) of wave w IS head
// h=w*4+oti: lane(kb,r16) holds U[q=qt*16+r16][d=kb*4+e]. The entire
// attention phase runs in this layout:
//   V[d]   : DPP allreduce over r16 (the 16-lane DPP row = fixed kb).
//   s[q]   : per-lane partial over its 4 d's, then shfl_xor 16/32 over kb.
//   softmax: no-max exp2; es via scalar DPP allreduce over r16.
//   out[d] : interleaved DPP allreduce over r16.
//   ss     : per-lane sum of 4 squares, shfl_xor 16/32 over kb.
//   store  : r16==0 lanes write b128 (head h, d=kb*4..kb*4+3).
__global__ __launch_bounds__(256, 5) void caps_kernel(
    const float* __restrict__ x,     // (B,T,32,8)
    const float* __restrict__ Bw,    // (T,16,1,32)
    const uint4* __restrict__ Kp,    // packed bf16 K fragments (+bias row)
    float* __restrict__ out)         // (B,T,16,16)
{
    const int bt  = blockIdx.x;
    const int t   = bt & (T_DIM - 1);
    const int tid = threadIdx.x;
    const int l   = tid & 63;
    const int w   = tid >> 6;
    const int kb  = l >> 4;
    const int r16 = l & 15;

    // ---- Bw prefetch: q=r16 and q=r16+16 for each head this wave owns ----
    float bwq0[4], bwq1[4];
    const float* bwt = Bw + (size_t)t * 512;
    #pragma unroll
    for (int oti = 0; oti < 4; ++oti) {
        const int h = w * 4 + oti;
        bwq0[oti] = bwt[h * 32 + r16];
        bwq1[oti] = bwt[h * 32 + 16 + r16];
    }

    // ---- B fragments: X^T columns (kt == kb); kb==3 = bias partner 1.0 ----
    short8 bx[2];
    if (kb == 3) {
        union { short8 s; uint4 u; } one;
        one.u = make_uint4(0x00003F80u, 0u, 0u, 0u);   // bf16(1.0) at e0
        bx[0] = bx[1] = one.s;
    } else {
        const int  tt    = t + kb - 1;
        const bool valid = (tt >= 0) && (tt < T_DIM);
        #pragma unroll
        for (int qt = 0; qt < 2; ++qt) {
            float4 x0 = make_float4(0.f, 0.f, 0.f, 0.f), x1 = x0;
            if (valid) {
                const float* xp = x + ((size_t)(bt + kb - 1) * 256 + (qt * 16 + r16) * 8);
                x0 = *reinterpret_cast<const float4*>(xp);
                x1 = *reinterpret_cast<const float4*>(xp + 4);
            }
            union { short8 s; uint4 u; } bu;
            bu.u.x = pk_bf16(x0.x, x0.y);
            bu.u.y = pk_bf16(x0.z, x0.w);
            bu.u.z = pk_bf16(x1.x, x1.y);
            bu.u.w = pk_bf16(x1.z, x1.w);
            bx[qt] = bu.s;
        }
    }

    // ---- A fragments from pre-packed Kp (coalesced b128, L1-hot) ----
    short8 af[4];
    #pragma unroll
    for (int oti = 0; oti < 4; ++oti) {
        union { short8 s; uint4 u; } au;
        au.u = Kp[kb * 256 + w * 64 + oti * 16 + r16];
        af[oti] = au.s;
    }

    // ---- conv MFMAs: acc[qt][oti][e] = U[qt*16+r16][w*64+oti*16+kb*4+e] ----
    const f32x4 z = (f32x4){0.f, 0.f, 0.f, 0.f};
    f32x4 acc[2][4];
    #pragma unroll
    for (int qt = 0; qt < 2; ++qt)
        #pragma unroll
        for (int oti = 0; oti < 4; ++oti)
            acc[qt][oti] = __builtin_amdgcn_mfma_f32_16x16x32_bf16(
                af[oti], bx[qt], z, 0, 0, 0);

    // ---- attention per head, all in-register / cross-lane ----
    const float C2 = 0.51011597846f;   // (1/sqrt(8)) * log2(e)
    #pragma unroll
    for (int oti = 0; oti < 4; ++oti) {
        const int h = w * 4 + oti;

        // relu'd U values this lane owns
        float u0[4], u1[4];
        #pragma unroll
        for (int e = 0; e < 4; ++e) {
            u0[e] = fmaxf(acc[0][oti][e], 0.f);
            u1[e] = fmaxf(acc[1][oti][e], 0.f);
        }

        // V[d=kb*4+e] = sum_q U[q][d]: qt-add then DPP allreduce over r16
        float v0 = u0[0] + u1[0], v1 = u0[1] + u1[1];
        float v2 = u0[2] + u1[2], v3 = u0[3] + u1[3];
        allred_add16_x4(v0, v1, v2, v3);

        // score partials over this lane's 4 d's; reduce over kb (xor 16,32)
        float s0 = v0 * u0[0] + v1 * u0[1] + v2 * u0[2] + v3 * u0[3];
        float s1 = v0 * u1[0] + v1 * u1[1] + v2 * u1[2] + v3 * u1[3];
        s0 += __shfl_xor(s0, 16);  s0 += __shfl_xor(s0, 32);
        s1 += __shfl_xor(s1, 16);  s1 += __shfl_xor(s1, 32);

        // softmax over 32 q (no max-sub; data-bounded). es over r16 via DPP.
        const float e0 = exp2f(s0 * C2), e1 = exp2f(s1 * C2);
        const float es = allred_add16_s(e0 + e1);
        const float inv = __builtin_amdgcn_rcpf(es);
        const float c0 = fmaf(e0, inv, bwq0[oti]);
        const float c1 = fmaf(e1, inv, bwq1[oti]);

        // out[d=kb*4+e] = sum_q c[q]U[q][d]: partial then DPP allreduce r16
        float o0 = c0 * u0[0] + c1 * u1[0];
        float o1 = c0 * u0[1] + c1 * u1[1];
        float o2 = c0 * u0[2] + c1 * u1[2];
        float o3 = c0 * u0[3] + c1 * u1[3];
        allred_add16_x4(o0, o1, o2, o3);

        // ss = sum_d out[d]^2: local 4 squares, reduce over kb (xor 16,32)
        float ss = o0 * o0 + o1 * o1 + o2 * o2 + o3 * o3;
        ss += __shfl_xor(ss, 16);
        ss += __shfl_xor(ss, 32);

        // norm gate, fold into one scale factor
        const float nrm = sqrtf(ss);
        const float g = ss * __builtin_amdgcn_rcpf(ss + 1.f) *
                        __builtin_amdgcn_rcpf(nrm + 1e-7f);

        if (r16 == 0) {
            float4 res = make_float4(o0 * g, o1 * g, o2 * g, o3 * g);
            *reinterpret_cast<float4*>(&out[(size_t)bt * 256 + h * 16 + kb * 4]) = res;
        }
    }
}

extern "C" void kernel_launch(void* const* d_in, const int* in_sizes, int n_in,
                              void* d_out, int out_size, void* d_ws, size_t ws_size,
                              hipStream_t stream) {
    const float* x    = (const float*)d_in[0];
    const float* K    = (const float*)d_in[1];
    const float* bias = (const float*)d_in[2];
    const float* Bw   = (const float*)d_in[3];
    float* out        = (float*)d_out;
    uint4* Kp         = (uint4*)d_ws;            // 16 KB scratch

    kpack_kernel<<<4, 256, 0, stream>>>(K, bias, Kp);

    const int B  = in_sizes[0] / (T_DIM * 32 * 8);   // = 8
    const int nb = B * T_DIM;                        // 8192 blocks
    caps_kernel<<<nb, 256, 0, stream>>>(x, Bw, Kp, out);
}

// Round 16
// 32.640 us; speedup vs baseline: 1.2227x; 1.2227x over previous
//
#include <hip/hip_runtime.h>

#define T_DIM 1024

typedef short short8 __attribute__((ext_vector_type(8)));
typedef float f32x4  __attribute__((ext_vector_type(4)));

__device__ __forceinline__ unsigned pk_bf16(float lo, float hi) {
    unsigned r;
    asm("v_cvt_pk_bf16_f32 %0, %1, %2" : "=v"(r) : "v"(lo), "v"(hi));
    return r;
}

// Pack K (3,8,256) f32 -> bf16 fragments; k-row 24 (kb==3,e==0) carries bias.
__global__ void kpack_kernel(const float* __restrict__ K,
                             const float* __restrict__ bias,
                             uint4* __restrict__ Kp) {
    const int kb  = blockIdx.x;
    const int col = threadIdx.x;
    uint4 wv = make_uint4(0u, 0u, 0u, 0u);
    if (kb < 3) {
        const float* kp = K + kb * 8 * 256 + col;
        wv.x = pk_bf16(kp[0 * 256], kp[1 * 256]);
        wv.y = pk_bf16(kp[2 * 256], kp[3 * 256]);
        wv.z = pk_bf16(kp[4 * 256], kp[5 * 256]);
        wv.w = pk_bf16(kp[6 * 256], kp[7 * 256]);
    } else {
        wv.x = pk_bf16(bias[col], 0.f);
    }
    Kp[kb * 256 + col] = wv;
}

// Single-instruction DPP allreduces over 16-lane rows (R10, verified).
__device__ __forceinline__ float allred_add16_s(float v) {
    asm volatile(
        "s_nop 1\n\t"
        "v_add_f32_dpp %0,%0,%0 row_ror:8 row_mask:0xf bank_mask:0xf\n\t"
        "s_nop 1\n\t"
        "v_add_f32_dpp %0,%0,%0 row_ror:4 row_mask:0xf bank_mask:0xf\n\t"
        "s_nop 1\n\t"
        "v_add_f32_dpp %0,%0,%0 row_ror:2 row_mask:0xf bank_mask:0xf\n\t"
        "s_nop 1\n\t"
        "v_add_f32_dpp %0,%0,%0 row_ror:1 row_mask:0xf bank_mask:0xf"
        : "+v"(v));
    return v;
}
__device__ __forceinline__ void allred_add16_x4(float& a, float& b, float& c, float& d) {
    asm volatile(
        "s_nop 1\n\t"
        "v_add_f32_dpp %0,%0,%0 row_ror:8 row_mask:0xf bank_mask:0xf\n\t"
        "v_add_f32_dpp %1,%1,%1 row_ror:8 row_mask:0xf bank_mask:0xf\n\t"
        "v_add_f32_dpp %2,%2,%2 row_ror:8 row_mask:0xf bank_mask:0xf\n\t"
        "v_add_f32_dpp %3,%3,%3 row_ror:8 row_mask:0xf bank_mask:0xf\n\t"
        "v_add_f32_dpp %0,%0,%0 row_ror:4 row_mask:0xf bank_mask:0xf\n\t"
        "v_add_f32_dpp %1,%1,%1 row_ror:4 row_mask:0xf bank_mask:0xf\n\t"
        "v_add_f32_dpp %2,%2,%2 row_ror:4 row_mask:0xf bank_mask:0xf\n\t"
        "v_add_f32_dpp %3,%3,%3 row_ror:4 row_mask:0xf bank_mask:0xf\n\t"
        "v_add_f32_dpp %0,%0,%0 row_ror:2 row_mask:0xf bank_mask:0xf\n\t"
        "v_add_f32_dpp %1,%1,%1 row_ror:2 row_mask:0xf bank_mask:0xf\n\t"
        "v_add_f32_dpp %2,%2,%2 row_ror:2 row_mask:0xf bank_mask:0xf\n\t"
        "v_add_f32_dpp %3,%3,%3 row_ror:2 row_mask:0xf bank_mask:0xf\n\t"
        "v_add_f32_dpp %0,%0,%0 row_ror:1 row_mask:0xf bank_mask:0xf\n\t"
        "v_add_f32_dpp %1,%1,%1 row_ror:1 row_mask:0xf bank_mask:0xf\n\t"
        "v_add_f32_dpp %2,%2,%2 row_ror:1 row_mask:0xf bank_mask:0xf\n\t"
        "v_add_f32_dpp %3,%3,%3 row_ror:1 row_mask:0xf bank_mask:0xf"
        : "+v"(a), "+v"(b), "+v"(c), "+v"(d));
}

__device__ __forceinline__ void wave_ds_fence() {
    asm volatile("s_waitcnt lgkmcnt(0)" ::: "memory");
}

template <int CODE>
__device__ __forceinline__ float swz_xor(float v) {
    return __int_as_float(__builtin_amdgcn_ds_swizzle(__float_as_int(v), CODE));
}

// bf16 U layout (R7, measured 0 bank conflicts): short index
// = q*256 + ((((o>>2)^(q&15))<<2) | (o&3)); b64 writes/reads conflict-free.
__device__ __forceinline__ int sidx(int q, int o) {
    return q * 256 + ((((o >> 2) ^ (q & 15)) << 2) | (o & 3));
}
__device__ __forceinline__ float bf_lo(unsigned u) { return __uint_as_float(u << 16); }
__device__ __forceinline__ float bf_hi(unsigned u) { return __uint_as_float(u & 0xffff0000u); }

// One block per (b,t), 4 waves, zero barriers, 16 KB LDS -> 8 blocks/CU.
// R13 body (best measured) with bf16 U tile to double residency
// (latency-bound regime: resident waves are the multiplier).
__global__ __launch_bounds__(256, 8) void caps_kernel(
    const float* __restrict__ x,     // (B,T,32,8)
    const float* __restrict__ Bw,    // (T,16,1,32)
    const uint4* __restrict__ Kp,    // packed bf16 K fragments (+bias row)
    float* __restrict__ out)         // (B,T,16,16)
{
    const int bt  = blockIdx.x;
    const int t   = bt & (T_DIM - 1);
    const int tid = threadIdx.x;
    const int l   = tid & 63;
    const int w   = tid >> 6;
    const int kb  = l >> 4;
    const int r16 = l & 15;
    const int n   = tid >> 4, j = tid & 15;

    __shared__ unsigned short U16[32 * 256];   // swizzled bf16 U

    // ---- Bw prefetch ----
    const float bwj0 = Bw[(size_t)t * 512 + n * 32 + j];
    const float bwj1 = Bw[(size_t)t * 512 + n * 32 + 16 + j];

    // ---- B fragments: X^T columns (kt == kb); kb==3 = bias partner 1.0 ----
    short8 bx[2];
    if (kb == 3) {
        union { short8 s; uint4 u; } one;
        one.u = make_uint4(0x00003F80u, 0u, 0u, 0u);   // bf16(1.0) at e0
        bx[0] = bx[1] = one.s;
    } else {
        const int  tt    = t + kb - 1;
        const bool valid = (tt >= 0) && (tt < T_DIM);
        #pragma unroll
        for (int qt = 0; qt < 2; ++qt) {
            float4 x0 = make_float4(0.f, 0.f, 0.f, 0.f), x1 = x0;
            if (valid) {
                const float* xp = x + ((size_t)(bt + kb - 1) * 256 + (qt * 16 + r16) * 8);
                x0 = *reinterpret_cast<const float4*>(xp);
                x1 = *reinterpret_cast<const float4*>(xp + 4);
            }
            union { short8 s; uint4 u; } bu;
            bu.u.x = pk_bf16(x0.x, x0.y);
            bu.u.y = pk_bf16(x0.z, x0.w);
            bu.u.z = pk_bf16(x1.x, x1.y);
            bu.u.w = pk_bf16(x1.z, x1.w);
            bx[qt] = bu.s;
        }
    }

    // ---- A fragments from pre-packed Kp (coalesced b128, L1-hot) ----
    short8 af[4];
    #pragma unroll
    for (int oti = 0; oti < 4; ++oti) {
        union { short8 s; uint4 u; } au;
        au.u = Kp[kb * 256 + w * 64 + oti * 16 + r16];
        af[oti] = au.s;
    }

    // ---- conv MFMAs ----
    const f32x4 z = (f32x4){0.f, 0.f, 0.f, 0.f};
    f32x4 acc[2][4];
    #pragma unroll
    for (int qt = 0; qt < 2; ++qt)
        #pragma unroll
        for (int oti = 0; oti < 4; ++oti)
            acc[qt][oti] = __builtin_amdgcn_mfma_f32_16x16x32_bf16(
                af[oti], bx[qt], z, 0, 0, 0);

    // ---- epilogue: relu -> bf16 -> swizzled b64 writes ----
    #pragma unroll
    for (int qt = 0; qt < 2; ++qt) {
        const int q = qt * 16 + r16;
        #pragma unroll
        for (int oti = 0; oti < 4; ++oti) {
            const int obase = w * 64 + oti * 16 + kb * 4;
            uint2 pk;
            pk.x = pk_bf16(fmaxf(acc[qt][oti][0], 0.f), fmaxf(acc[qt][oti][1], 0.f));
            pk.y = pk_bf16(fmaxf(acc[qt][oti][2], 0.f), fmaxf(acc[qt][oti][3], 0.f));
            *reinterpret_cast<uint2*>(&U16[sidx(q, obase)]) = pk;
        }
    }

    wave_ds_fence();   // all phase-2 reads touch only this wave's columns

    // ---- phase 2: thread = (head n, lane j) ----
    f32x4 r0[4], r1[4];
    #pragma unroll
    for (int i = 0; i < 4; ++i) {
        const uint2 a = *reinterpret_cast<const uint2*>(&U16[sidx(j,      n * 16 + 4 * i)]);
        const uint2 c = *reinterpret_cast<const uint2*>(&U16[sidx(j + 16, n * 16 + 4 * i)]);
        r0[i] = (f32x4){bf_lo(a.x), bf_hi(a.x), bf_lo(a.y), bf_hi(a.y)};
        r1[i] = (f32x4){bf_lo(c.x), bf_hi(c.x), bf_lo(c.y), bf_hi(c.y)};
    }

    // V[d] = sum_q U[q][d] (DPP allreduce over 16 lanes)
    f32x4 V[4];
    #pragma unroll
    for (int i = 0; i < 4; ++i) {
        V[i] = r0[i] + r1[i];
        float a = V[i][0], b = V[i][1], c = V[i][2], d = V[i][3];
        allred_add16_x4(a, b, c, d);
        V[i] = (f32x4){a, b, c, d};
    }

    // scores (unscaled dots)
    float s0 = 0.f, s1 = 0.f;
    #pragma unroll
    for (int i = 0; i < 4; ++i)
        #pragma unroll
        for (int c = 0; c < 4; ++c) {
            s0 = fmaf(V[i][c], r0[i][c], s0);
            s1 = fmaf(V[i][c], r1[i][c], s1);
        }

    // softmax over 32 q: exp(s/sqrt8) = exp2(s*C2); no max-sub (data-bounded)
    const float C2 = 0.51011597846f;   // (1/sqrt(8)) * log2(e)
    const float e0 = exp2f(s0 * C2), e1 = exp2f(s1 * C2);
    const float es = allred_add16_s(e0 + e1);
    const float inv = __builtin_amdgcn_rcpf(es);
    const float c0 = fmaf(e0, inv, bwj0);
    const float c1 = fmaf(e1, inv, bwj1);

    // per-lane partials for all 16 output components
    float op16[16];
    #pragma unroll
    for (int i = 0; i < 4; ++i)
        #pragma unroll
        for (int c = 0; c < 4; ++c)
            op16[4 * i + c] = fmaf(c0, r0[i][c], c1 * r1[i][c]);

    // butterfly reduce-scatter over the 16-lane group: lane j -> out[j]
    float v8[8];
    #pragma unroll
    for (int s = 0; s < 8; ++s) {
        const float kp = (j & 8) ? op16[s + 8] : op16[s];
        const float sd = (j & 8) ? op16[s] : op16[s + 8];
        v8[s] = kp + swz_xor<0x201F>(sd);
    }
    float v4[4];
    #pragma unroll
    for (int s = 0; s < 4; ++s) {
        const float kp = (j & 4) ? v8[s + 4] : v8[s];
        const float sd = (j & 4) ? v8[s] : v8[s + 4];
        v4[s] = kp + swz_xor<0x101F>(sd);
    }
    float v2[2];
    #pragma unroll
    for (int s = 0; s < 2; ++s) {
        const float kp = (j & 2) ? v4[s + 2] : v4[s];
        const float sd = (j & 2) ? v4[s] : v4[s + 2];
        v2[s] = kp + swz_xor<0x081F>(sd);
    }
    const float kp1 = (j & 1) ? v2[1] : v2[0];
    const float sd1 = (j & 1) ? v2[0] : v2[1];
    const float ox = kp1 + swz_xor<0x041F>(sd1);

    // norm gate: ss = sum_d out[d]^2 via scalar allreduce
    const float ss  = allred_add16_s(ox * ox);
    const float nrm = sqrtf(ss);
    const float res = ss * __builtin_amdgcn_rcpf(ss + 1.f) *
                      (ox * __builtin_amdgcn_rcpf(nrm + 1e-7f));

    out[(size_t)bt * 256 + tid] = res;
}

extern "C" void kernel_launch(void* const* d_in, const int* in_sizes, int n_in,
                              void* d_out, int out_size, void* d_ws, size_t ws_size,
                              hipStream_t stream) {
    const float* x    = (const float*)d_in[0];
    const float* K    = (const float*)d_in[1];
    const float* bias = (const float*)d_in[2];
    const float* Bw   = (const float*)d_in[3];
    float* out        = (float*)d_out;
    uint4* Kp         = (uint4*)d_ws;            // 16 KB scratch

    kpack_kernel<<<4, 256, 0, stream>>>(K, bias, Kp);

    const int B  = in_sizes[0] / (T_DIM * 32 * 8);   // = 8
    const int nb = B * T_DIM;                        // 8192 blocks
    caps_kernel<<<nb, 256, 0, stream>>>(x, Bw, Kp, out);
}